// Round 2
// baseline (258.466 us; speedup 1.0000x reference)
//
#include <hip/hip_runtime.h>

// out[h1,w1,c1,h2,w2,c2] =
//   gamma^(|h1-h2|+|w1-w2|+|c1-c2|) * (1 + spec_pe[c1,c2]*mean[h1,w1,c1]) * decay[c1]
// mean[h1,w1,c1] = Sh[h1]*Sh[w1]*Sc[c1] / 8192   (separable Manhattan mask mean)
// H=W=32, C=8. Output 67,108,864 fp32 = 256 MiB — pure write-bound generator.
//
// R1 restructure: block = one (h1,w1,c1) slice. All slice-level factors hoisted
// into 4 per-thread registers Kw[j]; inner loop over h2 is 1 broadcast ds_read +
// 4 muls + 1 dwordx4 store per 16 B/lane. (R0 had ~12 divergent ds_reads + ~10
// VALU per store -> LDS/VALU issue-bound at ~95 us vs ~43 us write roofline.)

__global__ __launch_bounds__(256) void manhattan_relpos_kernel(
    const float* __restrict__ decay,    // 8 elems
    const float* __restrict__ spec_pe,  // 64 elems
    float* __restrict__ out)            // 67108864 floats
{
    __shared__ float powtab[72];  // gamma^d
    __shared__ float Sh[32];      // sum_j gamma^|h-j|
    __shared__ float meanC[8];    // (sum_c2 gamma^|c1-c2|) / 8192
    __shared__ float A[64];       // gamma^|c1-c2| * decay[c1]
    __shared__ float SP[64];      // spec_pe[c1*8+c2]

    const int tid = threadIdx.x;

    if (tid < 72) {
        // log2(0.9) = -0.15200309344504997
        powtab[tid] = exp2f((float)tid * -0.15200309344504997f);
    }
    __syncthreads();
    if (tid < 32) {
        float s = 0.0f;
        #pragma unroll
        for (int j = 0; j < 32; ++j) s += powtab[abs(tid - j)];
        Sh[tid] = s;
    } else if (tid < 40) {
        const int c1 = tid - 32;
        float s = 0.0f;
        #pragma unroll
        for (int j = 0; j < 8; ++j) s += powtab[abs(c1 - j)];
        meanC[c1] = s * (1.0f / 8192.0f);
    } else if (tid >= 64 && tid < 128) {
        const int i = tid - 64;
        const int c1 = i >> 3, c2 = i & 7;
        A[i]  = powtab[abs(c1 - c2)] * decay[c1];
        SP[i] = spec_pe[i];
    }
    __syncthreads();

    // block -> slice (h1,w1,c1); slice-major order matches output layout.
    const int slice = blockIdx.x;           // 0..8191
    const int c1 = slice & 7;
    const int w1 = (slice >> 3) & 31;
    const int h1 = slice >> 8;

    // thread -> (half, w2, h2lo) within the 8192-float slice (2048 float4s)
    const int half = tid & 1;
    const int w2   = (tid >> 1) & 31;
    const int h2lo = tid >> 6;              // 0..3 (uniform per wave)

    const float pw = powtab[abs(w1 - w2)];
    const float m  = Sh[h1] * Sh[w1] * meanC[c1];
    const int cbase = (c1 << 3) + (half << 2);

    // Kw[j] = gamma^|w1-w2| * gamma^|c1-c2| * decay[c1] * (1 + spec*m)
    const float K0 = pw * A[cbase + 0] * fmaf(SP[cbase + 0], m, 1.0f);
    const float K1 = pw * A[cbase + 1] * fmaf(SP[cbase + 1], m, 1.0f);
    const float K2 = pw * A[cbase + 2] * fmaf(SP[cbase + 2], m, 1.0f);
    const float K3 = pw * A[cbase + 3] * fmaf(SP[cbase + 3], m, 1.0f);

    float4* outp = reinterpret_cast<float4*>(out) + slice * 2048 + tid;
    #pragma unroll
    for (int i = 0; i < 8; ++i) {
        const int h2 = (i << 2) | h2lo;
        const float ph = powtab[abs(h1 - h2)];   // wave-uniform broadcast read
        float4 v;
        v.x = ph * K0;
        v.y = ph * K1;
        v.z = ph * K2;
        v.w = ph * K3;
        outp[i << 8] = v;
    }
}

extern "C" void kernel_launch(void* const* d_in, const int* in_sizes, int n_in,
                              void* d_out, int out_size, void* d_ws, size_t ws_size,
                              hipStream_t stream) {
    // d_in[0] = x (values unused by the math)
    const float* decay   = (const float*)d_in[1];
    const float* spec_pe = (const float*)d_in[2];
    float* out = (float*)d_out;

    dim3 grid(8192), block(256);
    manhattan_relpos_kernel<<<grid, block, 0, stream>>>(decay, spec_pe, out);
}